// Round 13
// baseline (207.063 us; speedup 1.0000x reference)
//
#include <hip/hip_runtime.h>
#include <hip/hip_cooperative_groups.h>

namespace cg = cooperative_groups;

#define NROWS  500000
#define NCOLS  80
#define NCHUNK 10000000                 // float4 chunks in logits
#define GRID   1024
#define TPB    256
#define NTHREADS (GRID * TPB)           // 262,144
#define FULL_ITERS 38                   // 38 * 262,144 = 9,961,472
#define REM_BASE   9961472              // remainder chunks: 38,528

// d_ws float layout (every cell written before read on every call)
#define WS_MAXP 0        // [0 .. 1024)     phase-A per-block maxes
#define WS_PART 2048     // [2048 .. 3072)  per-block partial sums

// lean per-4: returns sum softplus + sum sigmoid - 4  (= log P + S3/P - 4)
__device__ __forceinline__ float quad_term(float x0, float x1, float x2, float x3) {
    float t0 = __expf(x0), t1 = __expf(x1), t2 = __expf(x2), t3 = __expf(x3);
    float b0 = 1.0f + t0, b1 = 1.0f + t1, b2 = 1.0f + t2, b3 = 1.0f + t3;
    float c01 = b0 * b1, c23 = b2 * b3;
    float P   = c01 * c23;
    float S3  = (b0 + b1) * c23 + (b2 + b3) * c01;
    return __logf(P) + S3 * __builtin_amdgcn_rcpf(P);
}

// correction for one fg row: full_term - 0.75*(sp - p)
__device__ __forceinline__ float corr_term(float x, float L) {
    float tv = __expf(x);
    float bb = 1.0f + tv;
    float rb = __builtin_amdgcn_rcpf(bb);
    float p  = tv * rb;                  // sigmoid(x)
    float sp = __logf(bb);               // softplus(x)
    float full;
    if (p <= L) {
        float spn = sp - x;              // softplus(-x)
        full = 0.25f * (spn * L + (p - L));
    } else {
        full = 0.75f * (sp * (1.0f - L) + (L - p));
    }
    return full - 0.75f * (sp - p);
}

// ---------------------------------------------------------------------------
// Single cooperative kernel. 1024 blocks x 256 thr = 4 blocks/CU exactly
// (launch_bounds caps VGPR so all blocks co-resident). Phases:
//  A: max iou over fg rows (each thread: rows tid, tid+262144) -> block maxes
//  sync
//  B: every block reduces the 1024 maxes -> invM; correction for the same
//     2 rows (targets L2-hot from A); then the 160 MB stream, 38 full
//     chunk-iters + checked remainder. Block partial -> ws.
//  sync
//  C: block 0 sums 1024 partials -> out[0].
// ---------------------------------------------------------------------------
__global__ void __launch_bounds__(TPB, 4)
coop_kernel(const float4* __restrict__ logits4,
            const float* __restrict__ logits,
            const float2* __restrict__ targets,
            float* __restrict__ ws,
            float* __restrict__ out) {
    cg::grid_group grid = cg::this_grid();
    const unsigned t   = threadIdx.x;
    const unsigned b   = blockIdx.x;
    const unsigned tid = b * TPB + t;
    const int lane = t & 63, wid = t >> 6;
    __shared__ float red[TPB / 64];
    __shared__ float s_invm;

    // ---------------- Phase A: max scan ----------------
    float vmax = 0.0f;
    {
        float2 t0 = targets[tid];                    // tid < 262144 < NROWS
        if ((int)t0.x >= 1) vmax = t0.y;
        unsigned r1 = tid + (unsigned)NTHREADS;
        if (r1 < (unsigned)NROWS) {
            float2 t1 = targets[r1];
            if ((int)t1.x >= 1) vmax = fmaxf(vmax, t1.y);
        }
    }
    #pragma unroll
    for (int off = 32; off > 0; off >>= 1)
        vmax = fmaxf(vmax, __shfl_xor(vmax, off));
    if (lane == 0) red[wid] = vmax;
    __syncthreads();
    if (t == 0) {
        float m = fmaxf(fmaxf(red[0], red[1]), fmaxf(red[2], red[3]));
        ws[WS_MAXP + b] = m;
    }
    grid.sync();

    // ---------------- Phase B ----------------
    // invM: every block reduces the 1024 block maxes (4 KB, L2-hot)
    {
        const float* maxp = ws + WS_MAXP;
        float m = fmaxf(fmaxf(maxp[t], maxp[t + 256]),
                        fmaxf(maxp[t + 512], maxp[t + 768]));
        #pragma unroll
        for (int off = 32; off > 0; off >>= 1)
            m = fmaxf(m, __shfl_xor(m, off));
        __syncthreads();                 // red[] reuse (phase A done)
        if (lane == 0) red[wid] = m;
        __syncthreads();
        if (t == 0) {
            float mm = fmaxf(fmaxf(red[0], red[1]), fmaxf(red[2], red[3]));
            s_invm = __builtin_amdgcn_rcpf(mm);
        }
        __syncthreads();
    }
    const float invM = s_invm;

    // correction for this thread's two rows (targets L2-hot from phase A)
    float acc_c = 0.0f;
    {
        float2 t0 = targets[tid];
        int c0 = (int)t0.x - 1;
        if (c0 >= 0)
            acc_c += corr_term(logits[tid * (unsigned)NCOLS + (unsigned)c0],
                               t0.y * invM);
        unsigned r1 = tid + (unsigned)NTHREADS;
        if (r1 < (unsigned)NROWS) {
            float2 t1 = targets[r1];
            int c1 = (int)t1.x - 1;
            if (c1 >= 0)
                acc_c += corr_term(logits[r1 * (unsigned)NCOLS + (unsigned)c1],
                                   t1.y * invM);
        }
    }

    // the 160 MB stream
    float acc = 0.0f;
    #pragma unroll 4
    for (int i = 0; i < FULL_ITERS; ++i) {
        float4 x4 = logits4[tid + (unsigned)i * NTHREADS];
        acc += quad_term(x4.x, x4.y, x4.z, x4.w);
    }
    {
        unsigned rem = (unsigned)REM_BASE + tid;
        if (rem < (unsigned)NCHUNK) {
            float4 x4 = logits4[rem];
            acc += quad_term(x4.x, x4.y, x4.z, x4.w) - 4.0f;
        }
    }
    acc = 0.75f * (acc - 4.0f * FULL_ITERS) + acc_c;

    // block reduce -> partial
    #pragma unroll
    for (int off = 32; off > 0; off >>= 1)
        acc += __shfl_xor(acc, off);
    __syncthreads();                     // red[] reuse
    if (lane == 0) red[wid] = acc;
    __syncthreads();
    if (t == 0) {
        float s = (red[0] + red[1]) + (red[2] + red[3]);
        ws[WS_PART + b] = s;
    }
    grid.sync();

    // ---------------- Phase C: final reduce (block 0) ----------------
    if (b == 0) {
        const float* part = ws + WS_PART;
        float a = (part[t] + part[t + 256]) + (part[t + 512] + part[t + 768]);
        #pragma unroll
        for (int off = 32; off > 0; off >>= 1)
            a += __shfl_xor(a, off);
        __syncthreads();                 // red[] reuse
        if (lane == 0) red[wid] = a;
        __syncthreads();
        if (t == 0)
            out[0] = (red[0] + red[1]) + (red[2] + red[3]);
    }
}

extern "C" void kernel_launch(void* const* d_in, const int* in_sizes, int n_in,
                              void* d_out, int out_size, void* d_ws, size_t ws_size,
                              hipStream_t stream) {
    const float4* logits4 = (const float4*)d_in[0];
    const float*  logits  = (const float*)d_in[0];
    const float2* targets = (const float2*)d_in[1];
    float* out = (float*)d_out;
    float* ws  = (float*)d_ws;

    void* args[] = { (void*)&logits4, (void*)&logits, (void*)&targets,
                     (void*)&ws, (void*)&out };
    hipLaunchCooperativeKernel((void*)coop_kernel, dim3(GRID), dim3(TPB),
                               args, 0, stream);
}